// Round 2
// baseline (527.089 us; speedup 1.0000x reference)
//
#include <hip/hip_runtime.h>
#include <hip/hip_cooperative_groups.h>
#include <math.h>

#define ALPHA 0.42f
#define H 1024
#define W 1024
#define NCH 48
#define BH 64           // rows per band; grid (16,48) = 768 blocks = 3/CU, fully resident

typedef float nfloat4 __attribute__((ext_vector_type(4)));

__device__ __forceinline__ float sigf(float x) {
    return __builtin_amdgcn_rcpf(1.0f + __expf(-x));
}

// LDS handoff barrier that does NOT drain vmcnt (keeps the global prefetch
// ring in flight across the barrier). lgkmcnt(0) retires this wave's ds ops.
__device__ __forceinline__ void block_sync_lds() {
    asm volatile("s_waitcnt lgkmcnt(0)" ::: "memory");
    __builtin_amdgcn_s_barrier();
    asm volatile("" ::: "memory");
}

// ---------------------------------------------------------------------------
// Phase 1: register-rolling vertical walk, 2-slot LDS row ring for the
// horizontal halo, global prefetch ring deepened to 4 rows (distance-4
// covers ~HBM latency at 3 waves/SIMD). Emits per-channel score atomically.
// ---------------------------------------------------------------------------
__device__ __forceinline__ void score_phase(const float* __restrict__ logits,
                                            float* __restrict__ scores,
                                            int bandIdx, int ch, int tid) {
    __shared__ __align__(16) float lrow[2][1032];   // col c at idx c+4; borders zero
    __shared__ float red[4];
    const int lane = tid & 63;
    const int wvi  = tid >> 6;
    const int band = bandIdx * BH;
    const int c4   = wvi * 256 + lane * 4;
    const float* gbase = logits + (size_t)ch * (H * W) + c4;

    if (tid < 8) {                                   // zero borders once
        int idx = (tid & 3) + ((tid & 4) ? 1028 : 0);
        lrow[0][idx] = 0.f;
        lrow[1][idx] = 0.f;
    }

    const float cvar  = (1.0f - ALPHA) * (1.0f / 49.0f);
    const float wfxc0 = cvar * (float)(7 - max(0, 3 - (c4 + 0)) - max(0, (c4 + 0) - (W - 4)));
    const float wfxc1 = cvar * (float)(7 - max(0, 3 - (c4 + 1)) - max(0, (c4 + 1) - (W - 4)));
    const float wfxc2 = cvar * (float)(7 - max(0, 3 - (c4 + 2)) - max(0, (c4 + 2) - (W - 4)));
    const float wfxc3 = cvar * (float)(7 - max(0, 3 - (c4 + 3)) - max(0, (c4 + 3) - (W - 4)));

    float4 vb[4];                                    // global prefetch ring, depth 4
    float srm[8], sr0[8], sr1[8], sr2[8], sr3[8], srp[8];
    float rsA[8], rsB[8], rsC[8], rsD[8];
    float vs0 = 0.f, vs1 = 0.f, vs2 = 0.f, vs3 = 0.f, acc = 0.f;
    #pragma unroll
    for (int k = 0; k < 8; ++k) { rsA[k] = rsB[k] = rsC[k] = rsD[k] = 0.f; }

    auto LOADROW = [&](int g, int slot) {
        int gc = min(max(g, 0), H - 1);
        vb[slot] = *(const float4*)(gbase + ((size_t)gc << 10));
    };

    auto STEP = [&](int n, int s8, int s4, int s2, bool doLoad, bool doEmit) {
        const int g = band - 3 + n;                  // row being ingested (wave-uniform)
        float4 raw = vb[s4];
        float q0 = 0.f, q1 = 0.f, q2 = 0.f, q3 = 0.f;
        if (g >= 0 && g < H) {
            q0 = sigf(raw.x); q1 = sigf(raw.y); q2 = sigf(raw.z); q3 = sigf(raw.w);
        }
        *(float4*)&lrow[s2][c4 + 4] = make_float4(q0, q1, q2, q3);
        if (doLoad) LOADROW(g + 4, s4);              // refill the slot just consumed
        block_sync_lds();
        float4 hl = *(const float4*)&lrow[s2][c4];       // cols c4-4..c4-1
        float4 hr = *(const float4*)&lrow[s2][c4 + 8];   // cols c4+4..c4+7
        float l1 = hl.y, l2 = hl.z, l3 = hl.w;
        float r0 = hr.x, r1 = hr.y, r2 = hr.z;
        float a = ((l1 + l2) + (l3 + q0)) + ((q1 + q2) + q3);
        float b = a - l1 + r0;
        float c = b - l2 + r1;
        float d = c - l3 + r2;
        const int old = (s8 + 1) & 7;
        vs0 += a - rsA[old]; vs1 += b - rsB[old]; vs2 += c - rsC[old]; vs3 += d - rsD[old];
        rsA[s8] = a; rsB[s8] = b; rsC[s8] = c; rsD[s8] = d;
        srm[s8] = l3; sr0[s8] = q0; sr1[s8] = q1; sr2[s8] = q2; sr3[s8] = q3; srp[s8] = r0;
        if (doEmit) {                                // emit row y = g-3
            const int Y = g - 3;
            float fy = (float)(7 - max(0, 3 - Y) - max(0, Y - (H - 4)));
            float wf0 = fy * wfxc0, wf1 = fy * wfxc1, wf2 = fy * wfxc2, wf3 = fy * wfxc3;
            const int sA = (s8 + 4) & 7, sB = (s8 + 5) & 7, sC = (s8 + 6) & 7;
            float A0 = srm[sA], A1 = sr0[sA], A2 = sr1[sA], A3 = sr2[sA], A4 = sr3[sA], A5 = srp[sA];
            float B0 = srm[sB], B1 = sr0[sB], B2 = sr1[sB], B3 = sr2[sB], B4 = sr3[sB], B5 = srp[sB];
            float C0 = srm[sC], C1 = sr0[sC], C2 = sr1[sC], C3 = sr2[sC], C4 = sr3[sC], C5 = srp[sC];
            float t0 = A0 + C0, t1 = A1 + C1, t2 = A2 + C2, t3 = A3 + C3, t4 = A4 + C4, t5 = A5 + C5;
            float u0 = A0 - C0, u1 = A1 - C1, u2 = A2 - C2, u3 = A3 - C3, u4 = A4 - C4, u5 = A5 - C5;
            auto PIXF = [&](float tp, float tp1, float tp2, float Bp, float Bp1, float Bp2,
                            float up, float up1, float up2, float vsv, float wf) {
                float sgx = (tp - tp2) + 2.f * (Bp - Bp2);
                float sgy = (up + up2) + 2.f * up1;
                float lp  = (Bp + Bp2) + tp1 - 4.f * Bp1;
                float edge = __builtin_amdgcn_sqrtf(sgx * sgx + sgy * sgy) + 0.5f * fabsf(lp);
                float dd = Bp1 - vsv * (1.f / 49.f);
                acc += ALPHA * edge + wf * (dd * dd);
            };
            PIXF(t0, t1, t2, B0, B1, B2, u0, u1, u2, vs0, wf0);
            PIXF(t1, t2, t3, B1, B2, B3, u1, u2, u3, vs1, wf1);
            PIXF(t2, t3, t4, B2, B3, B4, u2, u3, u4, vs2, wf2);
            PIXF(t3, t4, t5, B3, B4, B5, u3, u4, u5, vs3, wf3);
        }
    };

    // ingest rows band-3 .. band+66 (70 steps), emit rows band .. band+63
    LOADROW(band - 3, 0);
    LOADROW(band - 2, 1);
    LOADROW(band - 1, 2);
    LOADROW(band + 0, 3);
    STEP(0, 0, 0, 0, true, false);
    STEP(1, 1, 1, 1, true, false);
    STEP(2, 2, 2, 0, true, false);
    STEP(3, 3, 3, 1, true, false);
    STEP(4, 4, 0, 0, true, false);
    STEP(5, 5, 1, 1, true, false);
    STEP(6, 6, 2, 0, true, true);
    STEP(7, 7, 3, 1, true, true);
    #pragma unroll 1
    for (int nn = 8; nn < BH; nn += 8) {             // n = 8..63; slots constant per k
        #pragma unroll
        for (int k = 0; k < 8; ++k)
            STEP(nn + k, k, k & 3, k & 1, true, true);
    }
    STEP(64, 0, 0, 0, true,  true);
    STEP(65, 1, 1, 1, true,  true);
    STEP(66, 2, 2, 0, false, true);
    STEP(67, 3, 3, 1, false, true);
    STEP(68, 4, 0, 0, false, true);
    STEP(69, 5, 1, 1, false, true);

    #pragma unroll
    for (int off = 32; off > 0; off >>= 1) acc += __shfl_down(acc, off);
    if (lane == 0) red[wvi] = acc;
    __syncthreads();
    if (tid == 0) atomicAdd(&scores[ch], red[0] + red[1] + red[2] + red[3]);
}

// ---------------------------------------------------------------------------
// Phase 2: out[b] = sum_s w[b,s]*logits[b,s]. 768 blocks grid-stride over
// 4M float4. Per-image weights computed once per block into LDS; scores read
// with agent scope (atomicAdd results live at the coherent point). Logits are
// L3-resident from phase 1; nt store keeps output from polluting LLC.
// ---------------------------------------------------------------------------
__device__ __forceinline__ void fuse_phase(const float* __restrict__ logits,
                                           const float* __restrict__ scores,
                                           const float* __restrict__ lw,
                                           float* __restrict__ out,
                                           int bid, int tid) {
    __shared__ float wds[48];
    if (tid < 16) {
        float l0 = lw[0], l1 = lw[1], l2 = lw[2];
        float mx = fmaxf(l0, fmaxf(l1, l2));
        float e0 = __expf(l0 - mx), e1 = __expf(l1 - mx), e2 = __expf(l2 - mx);
        float inv = __builtin_amdgcn_rcpf(e0 + e1 + e2);
        float s0 = __hip_atomic_load(&scores[tid * 3 + 0], __ATOMIC_RELAXED, __HIP_MEMORY_SCOPE_AGENT);
        float s1 = __hip_atomic_load(&scores[tid * 3 + 1], __ATOMIC_RELAXED, __HIP_MEMORY_SCOPE_AGENT);
        float s2 = __hip_atomic_load(&scores[tid * 3 + 2], __ATOMIC_RELAXED, __HIP_MEMORY_SCOPE_AGENT);
        float itot = __builtin_amdgcn_rcpf(s0 + s1 + s2 + 1e-6f);
        wds[tid * 3 + 0] = 0.5f * (s0 * itot + e0 * inv);
        wds[tid * 3 + 1] = 0.5f * (s1 * itot + e1 * inv);
        wds[tid * 3 + 2] = 0.5f * (s2 * itot + e2 * inv);
    }
    __syncthreads();

    const size_t NTH = 768 * 256;                    // 196608 threads total
    const size_t TOT = (size_t)16 * 262144;          // 4,194,304 output float4
    size_t base = (size_t)bid * 256 + tid;

    auto BODY = [&](size_t i) {
        size_t b = i >> 18;
        size_t r = i & 262143;
        float w0 = wds[b * 3 + 0], w1 = wds[b * 3 + 1], w2 = wds[b * 3 + 2];
        const nfloat4* pb = (const nfloat4*)logits + b * 3 * 262144 + r;
        nfloat4 x0 = pb[0];
        nfloat4 x1 = pb[262144];
        nfloat4 x2 = pb[524288];
        __builtin_nontemporal_store(x0 * w0 + x1 * w1 + x2 * w2, (nfloat4*)out + i);
    };

    #pragma unroll 3
    for (int k = 0; k < 21; ++k) BODY(base + (size_t)k * NTH);
    size_t i = base + 21 * NTH;
    if (i < TOT) BODY(i);
}

// ---------------------------------------------------------------------------
__global__ __launch_bounds__(256, 3)
void fused_kernel(const float* __restrict__ logits, float* __restrict__ scores,
                  const float* __restrict__ lw, float* __restrict__ out) {
    score_phase(logits, scores, blockIdx.x, blockIdx.y, threadIdx.x);
    __threadfence();
    cooperative_groups::this_grid().sync();
    fuse_phase(logits, scores, lw, out, blockIdx.y * gridDim.x + blockIdx.x, threadIdx.x);
}

// Fallback path (if cooperative launch is rejected under graph capture)
__global__ __launch_bounds__(256, 3)
void score_kernel(const float* __restrict__ logits, float* __restrict__ scores) {
    score_phase(logits, scores, blockIdx.x, blockIdx.y, threadIdx.x);
}

__global__ __launch_bounds__(256)
void fuse_kernel(const float* __restrict__ logits, const float* __restrict__ scores,
                 const float* __restrict__ lw, float* __restrict__ out) {
    fuse_phase(logits, scores, lw, out, blockIdx.x, threadIdx.x);
}

extern "C" void kernel_launch(void* const* d_in, const int* in_sizes, int n_in,
                              void* d_out, int out_size, void* d_ws, size_t ws_size,
                              hipStream_t stream) {
    const float* logits = (const float*)d_in[0];
    const float* lw     = (const float*)d_in[1];
    float* out    = (float*)d_out;
    float* scores = (float*)d_ws;    // 48 floats

    (void)hipMemsetAsync(d_ws, 0, NCH * sizeof(float), stream);

    void* args[] = {(void*)&logits, (void*)&scores, (void*)&lw, (void*)&out};
    hipError_t err = hipLaunchCooperativeKernel((const void*)fused_kernel,
                                                dim3(H / BH, NCH), dim3(256),
                                                args, 0, stream);
    if (err != hipSuccess) {
        (void)hipGetLastError();                     // clear sticky error
        score_kernel<<<dim3(H / BH, NCH), 256, 0, stream>>>(logits, scores);
        fuse_kernel<<<768, 256, 0, stream>>>(logits, scores, lw, out);
    }
}

// Round 3
// 385.513 us; speedup vs baseline: 1.3672x; 1.3672x over previous
//
#include <hip/hip_runtime.h>
#include <math.h>

#define ALPHA 0.42f
#define H 1024
#define W 1024
#define NCH 48
#define BH 32
#define NBANDS (H / BH)     // 32 bands; grid (32,48) = 1536 blocks -> 4/CU resident

typedef float nfloat4 __attribute__((ext_vector_type(4)));

__device__ __forceinline__ float sigf(float x) {
    return __builtin_amdgcn_rcpf(1.0f + __expf(-x));
}

// LDS handoff barrier that does NOT drain vmcnt: keeps the global prefetch
// ring in flight across the barrier. lgkmcnt(0) retires this wave's ds ops.
__device__ __forceinline__ void block_sync_lds() {
    asm volatile("s_waitcnt lgkmcnt(0)" ::: "memory");
    __builtin_amdgcn_s_barrier();
    asm volatile("" ::: "memory");
}

// ---------------------------------------------------------------------------
// score_kernel: register-rolling vertical walk; horizontal halo via a 4-slot
// LDS row ring, TWO rows per barrier (pair-steps) -> 19 barriers per block
// instead of 38. Global prefetch ring depth 4 (2 pairs ahead), issued before
// the sigmoid work. Per-(ch,band) partial written non-atomically to ws.
// Safety: pair p writes slots {2p&3,(2p+1)&3} before barrier Bp; readers of
// those slots retire before B(p+1) (lgkmcnt(0)); next write to the same slots
// is at pair p+2, after B(p+1) -> no race.
// ---------------------------------------------------------------------------
__global__ __launch_bounds__(256, 4)
void score_kernel(const float* __restrict__ logits, float* __restrict__ scores_ws) {
    __shared__ __align__(16) float lrow[4][1032];   // col c at idx c+4; borders zero
    __shared__ float red[4];
    const int tid  = threadIdx.x;
    const int lane = tid & 63;
    const int wvi  = tid >> 6;
    const int ch   = blockIdx.y;
    const int band = blockIdx.x * BH;
    const int c4   = wvi * 256 + lane * 4;
    const float* gbase = logits + (size_t)ch * (H * W) + c4;

    if (tid < 32) {                                  // zero 4 slots' borders once
        int s   = tid >> 3;
        int idx = (tid & 3) + ((tid & 4) ? 1028 : 0);
        lrow[s][idx] = 0.f;
    }

    const float cvar  = (1.0f - ALPHA) * (1.0f / 49.0f);
    const float wfxc0 = cvar * (float)(7 - max(0, 3 - (c4 + 0)) - max(0, (c4 + 0) - (W - 4)));
    const float wfxc1 = cvar * (float)(7 - max(0, 3 - (c4 + 1)) - max(0, (c4 + 1) - (W - 4)));
    const float wfxc2 = cvar * (float)(7 - max(0, 3 - (c4 + 2)) - max(0, (c4 + 2) - (W - 4)));
    const float wfxc3 = cvar * (float)(7 - max(0, 3 - (c4 + 3)) - max(0, (c4 + 3) - (W - 4)));

    float4 vb[4];                                    // global prefetch ring, depth 4
    float srm[8], sr0[8], sr1[8], sr2[8], sr3[8], srp[8];
    float rsA[8], rsB[8], rsC[8], rsD[8];
    float vs0 = 0.f, vs1 = 0.f, vs2 = 0.f, vs3 = 0.f, acc = 0.f;
    #pragma unroll
    for (int k = 0; k < 8; ++k) { rsA[k] = rsB[k] = rsC[k] = rsD[k] = 0.f; }

    auto LOADROW = [&](int g, int slot) {
        int gc = min(max(g, 0), H - 1);
        vb[slot] = *(const float4*)(gbase + ((size_t)gc << 10));
    };

    // post-barrier work for one row: halo read, rolling sums, ring, emit
    auto INGEST = [&](int m, float q0, float q1, float q2, float q3, int sl, bool doEmit) {
        const int s8 = m & 7;
        float4 hl = *(const float4*)&lrow[sl][c4];       // cols c4-4..c4-1
        float4 hr = *(const float4*)&lrow[sl][c4 + 8];   // cols c4+4..c4+7
        float l1 = hl.y, l2 = hl.z, l3 = hl.w;
        float r0 = hr.x, r1 = hr.y, r2 = hr.z;
        float a = ((l1 + l2) + (l3 + q0)) + ((q1 + q2) + q3);
        float b = a - l1 + r0;
        float c = b - l2 + r1;
        float d = c - l3 + r2;
        const int old = (s8 + 1) & 7;                // row m-7 leaves vertical window
        vs0 += a - rsA[old]; vs1 += b - rsB[old]; vs2 += c - rsC[old]; vs3 += d - rsD[old];
        rsA[s8] = a; rsB[s8] = b; rsC[s8] = c; rsD[s8] = d;
        srm[s8] = l3; sr0[s8] = q0; sr1[s8] = q1; sr2[s8] = q2; sr3[s8] = q3; srp[s8] = r0;
        if (doEmit) {                                // emit row Y = band + m - 6
            const int Y = band + m - 6;
            float fy = (float)(7 - max(0, 3 - Y) - max(0, Y - (H - 4)));
            float wf0 = fy * wfxc0, wf1 = fy * wfxc1, wf2 = fy * wfxc2, wf3 = fy * wfxc3;
            const int sA = (s8 + 4) & 7, sB = (s8 + 5) & 7, sC = (s8 + 6) & 7;
            float A0 = srm[sA], A1 = sr0[sA], A2 = sr1[sA], A3 = sr2[sA], A4 = sr3[sA], A5 = srp[sA];
            float B0 = srm[sB], B1 = sr0[sB], B2 = sr1[sB], B3 = sr2[sB], B4 = sr3[sB], B5 = srp[sB];
            float C0 = srm[sC], C1 = sr0[sC], C2 = sr1[sC], C3 = sr2[sC], C4 = sr3[sC], C5 = srp[sC];
            float t0 = A0 + C0, t1 = A1 + C1, t2 = A2 + C2, t3 = A3 + C3, t4 = A4 + C4, t5 = A5 + C5;
            float u0 = A0 - C0, u1 = A1 - C1, u2 = A2 - C2, u3 = A3 - C3, u4 = A4 - C4, u5 = A5 - C5;
            auto PIXF = [&](float tp, float tp1, float tp2, float Bp, float Bp1, float Bp2,
                            float up, float up1, float up2, float vsv, float wf) {
                float sgx = (tp - tp2) + 2.f * (Bp - Bp2);
                float sgy = (up + up2) + 2.f * up1;
                float lp  = (Bp + Bp2) + tp1 - 4.f * Bp1;
                float edge = __builtin_amdgcn_sqrtf(sgx * sgx + sgy * sgy) + 0.5f * fabsf(lp);
                float dd = Bp1 - vsv * (1.f / 49.f);
                acc += ALPHA * edge + wf * (dd * dd);
            };
            PIXF(t0, t1, t2, B0, B1, B2, u0, u1, u2, vs0, wf0);
            PIXF(t1, t2, t3, B1, B2, B3, u1, u2, u3, vs1, wf1);
            PIXF(t2, t3, t4, B2, B3, B4, u2, u3, u4, vs2, wf2);
            PIXF(t3, t4, t5, B3, B4, B5, u3, u4, u5, vs3, wf3);
        }
    };

    // pair: ingest rows n and n+1 (global rows g, g+1), one barrier
    auto PAIR = [&](int n, bool doEmit, bool doLoad) {
        const int g   = band - 3 + n;
        const int sl0 = n & 3, sl1 = (n + 1) & 3;
        float4 raw0 = vb[sl0];
        float4 raw1 = vb[sl1];
        if (doLoad) { LOADROW(g + 4, sl0); LOADROW(g + 5, sl1); }   // issue early
        float p0 = 0.f, p1 = 0.f, p2 = 0.f, p3 = 0.f;
        float q0 = 0.f, q1 = 0.f, q2 = 0.f, q3 = 0.f;
        if (g >= 0 && g < H) {
            p0 = sigf(raw0.x); p1 = sigf(raw0.y); p2 = sigf(raw0.z); p3 = sigf(raw0.w);
        }
        if (g + 1 >= 0 && g + 1 < H) {
            q0 = sigf(raw1.x); q1 = sigf(raw1.y); q2 = sigf(raw1.z); q3 = sigf(raw1.w);
        }
        *(float4*)&lrow[sl0][c4 + 4] = make_float4(p0, p1, p2, p3);
        *(float4*)&lrow[sl1][c4 + 4] = make_float4(q0, q1, q2, q3);
        block_sync_lds();
        INGEST(n,     p0, p1, p2, p3, sl0, doEmit);
        INGEST(n + 1, q0, q1, q2, q3, sl1, doEmit);
    };

    // ingest rows band-3 .. band+34 (38 rows = 19 pairs); emit band .. band+31
    LOADROW(band - 3, 0);
    LOADROW(band - 2, 1);
    LOADROW(band - 1, 2);
    LOADROW(band + 0, 3);
    PAIR(0, false, true);
    PAIR(2, false, true);
    PAIR(4, false, true);
    PAIR(6, true,  true);
    #pragma unroll 1
    for (int nn = 8; nn <= 24; nn += 8) {            // pairs n = 8..31; slots constant
        PAIR(nn + 0, true, true);
        PAIR(nn + 2, true, true);
        PAIR(nn + 4, true, true);
        PAIR(nn + 6, true, true);
    }
    PAIR(32, true, true);                            // loads rows band+33, band+34
    PAIR(34, true, false);
    PAIR(36, true, false);

    #pragma unroll
    for (int off = 32; off > 0; off >>= 1) acc += __shfl_down(acc, off);
    if (lane == 0) red[wvi] = acc;
    __syncthreads();
    if (tid == 0)
        scores_ws[ch * NBANDS + blockIdx.x] = red[0] + red[1] + red[2] + red[3];
}

// ---------------------------------------------------------------------------
// fuse_kernel: out[b] = sum_s w[b,s]*logits[b,s]. Per-block (image-uniform)
// weight computation reduces the 32 band partials per channel via uniform
// scalar-cache loads. Cacheable logits loads (L3-resident after score);
// nontemporal stores (out never re-read). 4 float4/thread, 12 loads of ILP.
// ---------------------------------------------------------------------------
__global__ __launch_bounds__(256)
void fuse_kernel(const float* __restrict__ logits,
                 const float* __restrict__ scores_ws,
                 const float* __restrict__ lw,
                 float* __restrict__ out) {
    const size_t HW4 = (size_t)(H * W) / 4;          // 2^18 float4 per plane

    const int b = blockIdx.x >> 8;                   // 4096 blocks, 1024 f4/block
    const float* sp = scores_ws + (size_t)b * 3 * NBANDS;
    float s0 = 0.f, s1 = 0.f, s2 = 0.f;
    #pragma unroll
    for (int i = 0; i < NBANDS; ++i) {
        s0 += sp[i];
        s1 += sp[NBANDS + i];
        s2 += sp[2 * NBANDS + i];
    }

    float l0 = lw[0], l1 = lw[1], l2 = lw[2];
    float mx = fmaxf(l0, fmaxf(l1, l2));
    float e0 = __expf(l0 - mx), e1 = __expf(l1 - mx), e2 = __expf(l2 - mx);
    float inv = __builtin_amdgcn_rcpf(e0 + e1 + e2);
    float itot = __builtin_amdgcn_rcpf(s0 + s1 + s2 + 1e-6f);
    float w0 = 0.5f * (s0 * itot + e0 * inv);
    float w1 = 0.5f * (s1 * itot + e1 * inv);
    float w2 = 0.5f * (s2 * itot + e2 * inv);

    size_t i0 = (size_t)blockIdx.x * 1024 + threadIdx.x;
    size_t r  = i0 & (HW4 - 1);
    const nfloat4* pb = (const nfloat4*)logits + (size_t)b * 3 * HW4 + r;
    nfloat4* po = (nfloat4*)out + i0;
    #pragma unroll
    for (int k = 0; k < 4; ++k) {
        nfloat4 x0 = pb[k * 256];
        nfloat4 x1 = pb[k * 256 + HW4];
        nfloat4 x2 = pb[k * 256 + 2 * HW4];
        nfloat4 o = x0 * w0 + x1 * w1 + x2 * w2;
        __builtin_nontemporal_store(o, po + k * 256);
    }
}

extern "C" void kernel_launch(void* const* d_in, const int* in_sizes, int n_in,
                              void* d_out, int out_size, void* d_ws, size_t ws_size,
                              hipStream_t stream) {
    const float* logits = (const float*)d_in[0];
    const float* lw     = (const float*)d_in[1];
    float* out       = (float*)d_out;
    float* scores_ws = (float*)d_ws;   // 48*32 = 1536 floats, fully rewritten each run

    dim3 g1(NBANDS, NCH);              // (32, 48) = 1536 blocks
    score_kernel<<<g1, 256, 0, stream>>>(logits, scores_ws);

    fuse_kernel<<<4096, 256, 0, stream>>>(logits, scores_ws, lw, out);
}

// Round 4
// 332.735 us; speedup vs baseline: 1.5841x; 1.1586x over previous
//
#include <hip/hip_runtime.h>
#include <math.h>

#define ALPHA 0.42f
#define H 1024
#define W 1024
#define NCH 48
#define BH 64
#define NBANDS (H / BH)     // 16 bands; grid (16,48) = 768 blocks -> 3/CU, one clean round

typedef float nfloat4 __attribute__((ext_vector_type(4)));

__device__ __forceinline__ float sigf(float x) {
    return __builtin_amdgcn_rcpf(1.0f + __expf(-x));
}

// LDS handoff barrier that does NOT drain vmcnt: keeps the global prefetch
// ring in flight across the barrier. lgkmcnt(0) retires this wave's ds ops.
__device__ __forceinline__ void block_sync_lds() {
    asm volatile("s_waitcnt lgkmcnt(0)" ::: "memory");
    __builtin_amdgcn_s_barrier();
    asm volatile("" ::: "memory");
}

// ---------------------------------------------------------------------------
// score_kernel: register-rolling vertical walk; horizontal halo via a 4-slot
// LDS row ring, TWO rows per barrier (pair-steps) -> 35 barriers per block.
// Global prefetch ring depth 4 (2 pairs ahead), issued before the sigmoids.
// launch_bounds(256,3): VGPR cap ~170 -> NO spills (round 3's (256,4) made
// the allocator target 64 VGPRs and spill 185 MB of scratch; that tier jump
// is the regression this round reverts).
// LDS slot race check: pair p writes slots {n&3,(n+1)&3} pre-barrier-Bp,
// reads them post-Bp; those reads retire before B(p+1) (lgkmcnt(0)); the
// next write to the same slots is in pair p+2, after B(p+1) -> safe.
// ---------------------------------------------------------------------------
__global__ __launch_bounds__(256, 3)
void score_kernel(const float* __restrict__ logits, float* __restrict__ scores_ws) {
    __shared__ __align__(16) float lrow[4][1032];   // col c at idx c+4; borders zero
    __shared__ float red[4];
    const int tid  = threadIdx.x;
    const int lane = tid & 63;
    const int wvi  = tid >> 6;
    const int ch   = blockIdx.y;
    const int band = blockIdx.x * BH;
    const int c4   = wvi * 256 + lane * 4;
    const float* gbase = logits + (size_t)ch * (H * W) + c4;

    if (tid < 32) {                                  // zero 4 slots' borders once
        int s   = tid >> 3;
        int idx = (tid & 3) + ((tid & 4) ? 1028 : 0);
        lrow[s][idx] = 0.f;
    }

    const float cvar  = (1.0f - ALPHA) * (1.0f / 49.0f);
    const float wfxc0 = cvar * (float)(7 - max(0, 3 - (c4 + 0)) - max(0, (c4 + 0) - (W - 4)));
    const float wfxc1 = cvar * (float)(7 - max(0, 3 - (c4 + 1)) - max(0, (c4 + 1) - (W - 4)));
    const float wfxc2 = cvar * (float)(7 - max(0, 3 - (c4 + 2)) - max(0, (c4 + 2) - (W - 4)));
    const float wfxc3 = cvar * (float)(7 - max(0, 3 - (c4 + 3)) - max(0, (c4 + 3) - (W - 4)));

    float4 vb[4];                                    // global prefetch ring, depth 4
    float srm[8], sr0[8], sr1[8], sr2[8], sr3[8], srp[8];
    float rsA[8], rsB[8], rsC[8], rsD[8];
    float vs0 = 0.f, vs1 = 0.f, vs2 = 0.f, vs3 = 0.f, acc = 0.f;
    #pragma unroll
    for (int k = 0; k < 8; ++k) { rsA[k] = rsB[k] = rsC[k] = rsD[k] = 0.f; }

    auto LOADROW = [&](int g, int slot) {
        int gc = min(max(g, 0), H - 1);
        vb[slot] = *(const float4*)(gbase + ((size_t)gc << 10));
    };

    // post-barrier work for one row: halo read, rolling sums, ring, emit
    auto INGEST = [&](int m, float q0, float q1, float q2, float q3, int sl, bool doEmit) {
        const int s8 = m & 7;
        float4 hl = *(const float4*)&lrow[sl][c4];       // cols c4-4..c4-1
        float4 hr = *(const float4*)&lrow[sl][c4 + 8];   // cols c4+4..c4+7
        float l1 = hl.y, l2 = hl.z, l3 = hl.w;
        float r0 = hr.x, r1 = hr.y, r2 = hr.z;
        float a = ((l1 + l2) + (l3 + q0)) + ((q1 + q2) + q3);
        float b = a - l1 + r0;
        float c = b - l2 + r1;
        float d = c - l3 + r2;
        const int old = (s8 + 1) & 7;                // row m-7 leaves vertical window
        vs0 += a - rsA[old]; vs1 += b - rsB[old]; vs2 += c - rsC[old]; vs3 += d - rsD[old];
        rsA[s8] = a; rsB[s8] = b; rsC[s8] = c; rsD[s8] = d;
        srm[s8] = l3; sr0[s8] = q0; sr1[s8] = q1; sr2[s8] = q2; sr3[s8] = q3; srp[s8] = r0;
        if (doEmit) {                                // emit row Y = band + m - 6
            const int Y = band + m - 6;
            float fy = (float)(7 - max(0, 3 - Y) - max(0, Y - (H - 4)));
            float wf0 = fy * wfxc0, wf1 = fy * wfxc1, wf2 = fy * wfxc2, wf3 = fy * wfxc3;
            const int sA = (s8 + 4) & 7, sB = (s8 + 5) & 7, sC = (s8 + 6) & 7;
            float A0 = srm[sA], A1 = sr0[sA], A2 = sr1[sA], A3 = sr2[sA], A4 = sr3[sA], A5 = srp[sA];
            float B0 = srm[sB], B1 = sr0[sB], B2 = sr1[sB], B3 = sr2[sB], B4 = sr3[sB], B5 = srp[sB];
            float C0 = srm[sC], C1 = sr0[sC], C2 = sr1[sC], C3 = sr2[sC], C4 = sr3[sC], C5 = srp[sC];
            float t0 = A0 + C0, t1 = A1 + C1, t2 = A2 + C2, t3 = A3 + C3, t4 = A4 + C4, t5 = A5 + C5;
            float u0 = A0 - C0, u1 = A1 - C1, u2 = A2 - C2, u3 = A3 - C3, u4 = A4 - C4, u5 = A5 - C5;
            auto PIXF = [&](float tp, float tp1, float tp2, float Bp, float Bp1, float Bp2,
                            float up, float up1, float up2, float vsv, float wf) {
                float sgx = (tp - tp2) + 2.f * (Bp - Bp2);
                float sgy = (up + up2) + 2.f * up1;
                float lp  = (Bp + Bp2) + tp1 - 4.f * Bp1;
                float edge = __builtin_amdgcn_sqrtf(sgx * sgx + sgy * sgy) + 0.5f * fabsf(lp);
                float dd = Bp1 - vsv * (1.f / 49.f);
                acc += ALPHA * edge + wf * (dd * dd);
            };
            PIXF(t0, t1, t2, B0, B1, B2, u0, u1, u2, vs0, wf0);
            PIXF(t1, t2, t3, B1, B2, B3, u1, u2, u3, vs1, wf1);
            PIXF(t2, t3, t4, B2, B3, B4, u2, u3, u4, vs2, wf2);
            PIXF(t3, t4, t5, B3, B4, B5, u3, u4, u5, vs3, wf3);
        }
    };

    // pair: ingest rows n and n+1 (global rows g, g+1), one barrier
    auto PAIR = [&](int n, bool doEmit, bool doLoad) {
        const int g   = band - 3 + n;
        const int sl0 = n & 3, sl1 = (n + 1) & 3;
        float4 raw0 = vb[sl0];
        float4 raw1 = vb[sl1];
        if (doLoad) { LOADROW(g + 4, sl0); LOADROW(g + 5, sl1); }   // issue early
        float p0 = 0.f, p1 = 0.f, p2 = 0.f, p3 = 0.f;
        float q0 = 0.f, q1 = 0.f, q2 = 0.f, q3 = 0.f;
        if (g >= 0 && g < H) {
            p0 = sigf(raw0.x); p1 = sigf(raw0.y); p2 = sigf(raw0.z); p3 = sigf(raw0.w);
        }
        if (g + 1 >= 0 && g + 1 < H) {
            q0 = sigf(raw1.x); q1 = sigf(raw1.y); q2 = sigf(raw1.z); q3 = sigf(raw1.w);
        }
        *(float4*)&lrow[sl0][c4 + 4] = make_float4(p0, p1, p2, p3);
        *(float4*)&lrow[sl1][c4 + 4] = make_float4(q0, q1, q2, q3);
        block_sync_lds();
        INGEST(n,     p0, p1, p2, p3, sl0, doEmit);
        INGEST(n + 1, q0, q1, q2, q3, sl1, doEmit);
    };

    // ingest rows band-3 .. band+66 (70 rows = 35 pairs); emit band .. band+63
    LOADROW(band - 3, 0);
    LOADROW(band - 2, 1);
    LOADROW(band - 1, 2);
    LOADROW(band + 0, 3);
    PAIR(0, false, true);
    PAIR(2, false, true);
    PAIR(4, false, true);
    PAIR(6, true,  true);
    #pragma unroll 1
    for (int nn = 8; nn <= 56; nn += 8) {            // pairs n = 8..62; slots constant
        PAIR(nn + 0, true, true);
        PAIR(nn + 2, true, true);
        PAIR(nn + 4, true, true);
        PAIR(nn + 6, true, true);
    }
    PAIR(64, true, true);                            // loads rows n=68,69 (last two)
    PAIR(66, true, false);
    PAIR(68, true, false);

    #pragma unroll
    for (int off = 32; off > 0; off >>= 1) acc += __shfl_down(acc, off);
    if (lane == 0) red[wvi] = acc;
    __syncthreads();
    if (tid == 0)
        scores_ws[ch * NBANDS + blockIdx.x] = red[0] + red[1] + red[2] + red[3];
}

// ---------------------------------------------------------------------------
// fuse_kernel: out[b] = sum_s w[b,s]*logits[b,s]. Per-block (image-uniform)
// weight computation reduces the 16 band partials per channel via uniform
// scalar-cache loads. Cacheable logits loads (L3-resident after score);
// nontemporal stores (out never re-read). 4 float4/thread, 12 loads of ILP.
// ---------------------------------------------------------------------------
__global__ __launch_bounds__(256)
void fuse_kernel(const float* __restrict__ logits,
                 const float* __restrict__ scores_ws,
                 const float* __restrict__ lw,
                 float* __restrict__ out) {
    const size_t HW4 = (size_t)(H * W) / 4;          // 2^18 float4 per plane

    const int b = blockIdx.x >> 8;                   // 4096 blocks, 1024 f4/block
    const float* sp = scores_ws + (size_t)b * 3 * NBANDS;
    float s0 = 0.f, s1 = 0.f, s2 = 0.f;
    #pragma unroll
    for (int i = 0; i < NBANDS; ++i) {
        s0 += sp[i];
        s1 += sp[NBANDS + i];
        s2 += sp[2 * NBANDS + i];
    }

    float l0 = lw[0], l1 = lw[1], l2 = lw[2];
    float mx = fmaxf(l0, fmaxf(l1, l2));
    float e0 = __expf(l0 - mx), e1 = __expf(l1 - mx), e2 = __expf(l2 - mx);
    float inv = __builtin_amdgcn_rcpf(e0 + e1 + e2);
    float itot = __builtin_amdgcn_rcpf(s0 + s1 + s2 + 1e-6f);
    float w0 = 0.5f * (s0 * itot + e0 * inv);
    float w1 = 0.5f * (s1 * itot + e1 * inv);
    float w2 = 0.5f * (s2 * itot + e2 * inv);

    size_t i0 = (size_t)blockIdx.x * 1024 + threadIdx.x;
    size_t r  = i0 & (HW4 - 1);
    const nfloat4* pb = (const nfloat4*)logits + (size_t)b * 3 * HW4 + r;
    nfloat4* po = (nfloat4*)out + i0;
    #pragma unroll
    for (int k = 0; k < 4; ++k) {
        nfloat4 x0 = pb[k * 256];
        nfloat4 x1 = pb[k * 256 + HW4];
        nfloat4 x2 = pb[k * 256 + 2 * HW4];
        nfloat4 o = x0 * w0 + x1 * w1 + x2 * w2;
        __builtin_nontemporal_store(o, po + k * 256);
    }
}

extern "C" void kernel_launch(void* const* d_in, const int* in_sizes, int n_in,
                              void* d_out, int out_size, void* d_ws, size_t ws_size,
                              hipStream_t stream) {
    const float* logits = (const float*)d_in[0];
    const float* lw     = (const float*)d_in[1];
    float* out       = (float*)d_out;
    float* scores_ws = (float*)d_ws;   // 48*16 floats, fully rewritten each run

    dim3 g1(NBANDS, NCH);              // (16, 48) = 768 blocks
    score_kernel<<<g1, 256, 0, stream>>>(logits, scores_ws);

    fuse_kernel<<<4096, 256, 0, stream>>>(logits, scores_ws, lw, out);
}